// Round 6
// baseline (338.280 us; speedup 1.0000x reference)
//
#include <hip/hip_runtime.h>
#include <cmath>

#define HW  (512*512)

typedef _Float16 half8  __attribute__((__vector_size__(16)));
typedef float    floatx4 __attribute__((__vector_size__(16)));

struct GeluCoef { float c[10]; };

__device__ __forceinline__ float sigmoid_f(float x){
    float e = __builtin_amdgcn_exp2f(-1.44269504f * x);
    return __builtin_amdgcn_rcpf(1.0f + e);
}

// Trans-free gelu: gelu(x) = x*(0.5 + xc*F(s)), s=x^2 clamped to 16,
// F = deg-9 poly in u = s/8-1, coeffs host-fit vs erf (max err ~3e-4).
__device__ __forceinline__ float gelu_poly(float x, const GeluCoef& C){
    float s  = x * x;
    float xc = fminf(fmaxf(x, -4.0f), 4.0f);
    float u  = fminf(__builtin_fmaf(s, 0.125f, -1.0f), 1.0f);
    float t  = C.c[9];
    #pragma unroll
    for (int k = 8; k >= 0; k--) t = __builtin_fmaf(u, t, C.c[k]);
    float w  = xc * t;                       // Phi(x) = 0.5 + w
    return __builtin_fmaf(x, w, 0.5f * x);   // x*Phi
}

// XOR swizzle: element (row, n) of the 128x256 f16 activation tile lives at
// f16 offset row*256 + (n ^ swz(row)); swz depends only on row&15.
__device__ __forceinline__ int swz(int row){
    return ((row & 3) << 3) ^ (((row >> 2) & 3) << 4);
}

// ---------------- prep: pack weights + per-batch c0, one launch ----------
__global__ void prep_all(const float* __restrict__ W1, const float* __restrict__ W2,
                         const float* __restrict__ W3, const float* __restrict__ emb,
                         const int* __restrict__ sidx, const float* __restrict__ W0,
                         const float* __restrict__ b0,
                         _Float16* __restrict__ wp, float* __restrict__ c0){
    int blk = blockIdx.x;
    int tid = threadIdx.x;
    if (blk < 528){
        int gid = blk * 256 + tid;
        if (gid < 131072){
            int i    = gid & 65535;
            int j    = i & 7;
            int lane = (i >> 3) & 63;
            int b2   = i >> 9;
            int ks = b2 >> 4, nt = b2 & 15;
            int k = ks*32 + ((lane >> 4) << 3) + j;
            int n = nt*16 + (lane & 15);
            const float* W = (gid < 65536) ? W1 : W2;
            wp[gid] = (_Float16)W[k*256 + n];
        } else {
            int i    = gid - 131072;          // 0..4095, W3 padded [256][16]
            int j    = i & 7;
            int lane = (i >> 3) & 63;
            int ks   = i >> 9;                // 0..7
            int k = ks*32 + ((lane >> 4) << 3) + j;
            int n = lane & 15;
            wp[gid] = (_Float16)((n < 3) ? W3[k*3 + n] : 0.0f);
        }
    } else {
        int b = blk - 528;
        int s = sidx[b];
        float acc = b0[tid];
        #pragma unroll 8
        for (int d = 0; d < 64; d++)
            acc = fmaf(emb[s*64 + d], W0[(3 + d)*256 + tid], acc);
        c0[b*256 + tid] = acc;
    }
}

// ---------------- fused MLP ----------------
__global__ __launch_bounds__(512, 4)
void nilut_main(const float* __restrict__ rgb,
                const float* __restrict__ W0,
                const float* __restrict__ b1v,
                const float* __restrict__ b2v,
                const float* __restrict__ b3v,
                const _Float16* __restrict__ wp,
                const float* __restrict__ c0,
                float* __restrict__ out,
                GeluCoef C){
    __shared__ __align__(16) _Float16 act[128 * 256];   // 65536 B, XOR-swizzled
    __shared__ __align__(16) float    w0s[1024];        // W0 rows 0..2 | c0[b]; reused as out bounce
    __shared__ __align__(16) float    rgbs[384];        // staged rgb tile [3][128]

    const int tid = threadIdx.x;
    const int wg  = blockIdx.x;
    const int pixbase = wg * 128;
    const int b   = pixbase >> 18;        // HW = 2^18
    const int hw0 = pixbase & (HW - 1);

    // stage W0[0:3] + c0[b] into LDS
    #pragma unroll
    for (int r = 0; r < 2; r++){
        int q = r*512 + tid;
        w0s[q] = (q < 768) ? W0[q] : c0[b*256 + (q - 768)];
    }
    // stage rgb tile (coalesced: 3 runs of 128 contiguous floats)
    if (tid < 384){
        int c = tid >> 7, row = tid & 127;
        rgbs[tid] = rgb[b*3*HW + c*HW + hw0 + row];
    }
    __syncthreads();

    // ---- layer 0: coeffs in registers, 8 cols x 8 rows per thread ----
    {
        int ng = tid & 31;                // fixed col group: n = ng*8 .. ng*8+7
        int rg = tid >> 5;                // row group: rows rg*8 .. rg*8+7
        floatx4 cw[4][2];
        #pragma unroll
        for (int p = 0; p < 4; p++){
            cw[p][0] = *(const floatx4*)&w0s[p*256 + ng*8];
            cw[p][1] = *(const floatx4*)&w0s[p*256 + ng*8 + 4];
        }
        #pragma unroll
        for (int hf = 0; hf < 2; hf++){
            floatx4 rv[3];
            #pragma unroll
            for (int c = 0; c < 3; c++)
                rv[c] = *(const floatx4*)&rgbs[c*128 + rg*8 + hf*4];
            #pragma unroll
            for (int r4 = 0; r4 < 4; r4++){
                int row = rg*8 + hf*4 + r4;
                float rr = rv[0][r4], gg = rv[1][r4], bb = rv[2][r4];
                half8 v;
                #pragma unroll
                for (int j = 0; j < 8; j++){
                    int hi = j >> 2, lo = j & 3;
                    float z = fmaf(rr, cw[0][hi][lo],
                              fmaf(gg, cw[1][hi][lo],
                              fmaf(bb, cw[2][hi][lo], cw[3][hi][lo])));
                    v[j] = (_Float16)gelu_poly(z, C);
                }
                *(half8*)&act[row*256 + ((ng*8) ^ swz(row))] = v;
            }
        }
    }
    __syncthreads();

    const int lane = tid & 63;
    const int wv   = tid >> 6;            // 0..7
    const int ln15 = lane & 15;
    const int quad = lane >> 4;
    const int q8   = quad * 8;
    const int qr   = quad * 4;
    const int sA   = swz(ln15);           // A-frag swizzle (row&15 == ln15)

    // ---- layers 1 and 2: 256x256 f16 MFMA, 2(row) x 4(col) wave split ----
    const _Float16* wl  = wp;             // Wp1
    const float* bias   = b1v;
    const int mh = wv >> 2, nh = wv & 3;
    const int rbase = mh * 64;
    const int cb16  = nh * 4;             // col base in 16-col units
    #pragma unroll 1
    for (int L = 0; L < 2; L++){
        floatx4 acc[4][4];
        #pragma unroll
        for (int nt = 0; nt < 4; nt++){
            float bv = bias[(cb16 + nt)*16 + ln15];
            #pragma unroll
            for (int m = 0; m < 4; m++)
                acc[m][nt] = (floatx4){bv, bv, bv, bv};
        }

        const half8* wp8 = (const half8*)wl;
        #pragma unroll 2
        for (int ks = 0; ks < 8; ks++){
            int k0 = (ks*32 + q8) ^ sA;
            half8 a[4];
            #pragma unroll
            for (int m = 0; m < 4; m++)
                a[m] = *(const half8*)&act[(rbase + m*16 + ln15)*256 + k0];
            #pragma unroll
            for (int nt = 0; nt < 4; nt++){
                half8 bf = wp8[(ks*16 + cb16 + nt)*64 + lane];
                #pragma unroll
                for (int m = 0; m < 4; m++)
                    acc[m][nt] = __builtin_amdgcn_mfma_f32_16x16x32_f16(a[m], bf, acc[m][nt], 0, 0, 0);
            }
        }
        __syncthreads();   // all reads of act done before overwrite
        #pragma unroll
        for (int nt = 0; nt < 4; nt++){
            int n = (cb16 + nt)*16 + ln15;
            #pragma unroll
            for (int m = 0; m < 4; m++){
                #pragma unroll
                for (int r = 0; r < 4; r++){
                    int row = rbase + m*16 + qr + r;
                    int se  = (r << 3) ^ (quad << 4);   // swz(qr + r)
                    act[row*256 + (n ^ se)] = (_Float16)gelu_poly(acc[m][nt][r], C);
                }
            }
        }
        __syncthreads();
        wl = wp + 65536;   // Wp2
        bias = b2v;
    }

    // ---- final layer 256 -> 3 (padded to 16) + sigmoid ----
    {
        const half8* wp8 = (const half8*)(wp + 131072);
        int rbf = wv * 16;                 // 8 waves x 16 rows = 128
        floatx4 ac = (floatx4){0.f,0.f,0.f,0.f};
        #pragma unroll
        for (int ks = 0; ks < 8; ks++){
            int k0 = (ks*32 + q8) ^ sA;
            half8 a  = *(const half8*)&act[(rbf + ln15)*256 + k0];
            half8 bf = wp8[ks*64 + lane];
            ac = __builtin_amdgcn_mfma_f32_16x16x32_f16(a, bf, ac, 0, 0, 0);
        }
        // w0s dead since layer 0 -> reuse as out bounce [3][128]
        if (ln15 < 3){
            float bv = b3v[ln15];
            #pragma unroll
            for (int r = 0; r < 4; r++){
                int row0 = rbf + qr + r;
                w0s[ln15*128 + row0] = sigmoid_f(ac[r] + bv);
            }
        }
        __syncthreads();
        if (tid < 96){
            int c  = tid >> 5;
            int i2 = tid & 31;
            float4* dst = (float4*)(out + (b*3 + c)*HW + hw0);
            dst[i2] = ((float4*)(w0s + c*128))[i2];
        }
    }
}

// Host-side weighted LS fit of G(s) = (Phi(sqrt(s))-0.5)/sqrt(s) on s in [0,16],
// poly in u = s/8-1, weight s^2 (equalizes gelu-space error). Pure host math.
static GeluCoef fit_gelu_poly(){
    const int M = 256, K = 10;
    double A[K][K], bv[K], cs[K];
    for (int r = 0; r < K; r++){ bv[r] = 0.0; for (int c = 0; c < K; c++) A[r][c] = 0.0; }
    for (int j = 0; j < M; j++){
        double u = -cos(M_PI * (j + 0.5) / M);   // Chebyshev nodes in [-1,1]
        double s = 8.0 * (u + 1.0);              // [0,16]
        double x = sqrt(s);
        double G = (x > 1e-8) ? (0.5 * erf(x * 0.7071067811865476) / x)
                              : 0.3989422804014327;
        double w = s * s + 0.1;
        double p[K]; p[0] = 1.0;
        for (int k = 1; k < K; k++) p[k] = p[k-1] * u;
        for (int r = 0; r < K; r++){
            bv[r] += w * G * p[r];
            for (int c = 0; c < K; c++) A[r][c] += w * p[r] * p[c];
        }
    }
    for (int col = 0; col < K; col++){           // gaussian elim, partial pivot
        int piv = col;
        for (int r = col + 1; r < K; r++) if (fabs(A[r][col]) > fabs(A[piv][col])) piv = r;
        if (piv != col){
            for (int c = 0; c < K; c++){ double t = A[col][c]; A[col][c] = A[piv][c]; A[piv][c] = t; }
            double t = bv[col]; bv[col] = bv[piv]; bv[piv] = t;
        }
        double d = A[col][col];
        for (int r = col + 1; r < K; r++){
            double f = A[r][col] / d;
            for (int c = col; c < K; c++) A[r][c] -= f * A[col][c];
            bv[r] -= f * bv[col];
        }
    }
    for (int r = K - 1; r >= 0; r--){
        double acc = bv[r];
        for (int c = r + 1; c < K; c++) acc -= A[r][c] * cs[c];
        cs[r] = acc / A[r][r];
    }
    GeluCoef out;
    for (int k = 0; k < K; k++) out.c[k] = (float)cs[k];
    return out;
}

extern "C" void kernel_launch(void* const* d_in, const int* in_sizes, int n_in,
                              void* d_out, int out_size, void* d_ws, size_t ws_size,
                              hipStream_t stream){
    const float* rgb = (const float*)d_in[0];
    const int*  sidx = (const int*) d_in[1];
    const float* emb = (const float*)d_in[2];
    const float* W0  = (const float*)d_in[3];
    const float* b0  = (const float*)d_in[4];
    const float* W1  = (const float*)d_in[5];
    const float* b1  = (const float*)d_in[6];
    const float* W2  = (const float*)d_in[7];
    const float* b2  = (const float*)d_in[8];
    const float* W3  = (const float*)d_in[9];
    const float* b3  = (const float*)d_in[10];
    float* out = (float*)d_out;

    _Float16* wp = (_Float16*)d_ws;                    // 135168 f16 = 270336 B
    float*    c0 = (float*)((char*)d_ws + 270336);     // 512 f32

    GeluCoef C = fit_gelu_poly();                      // host-only math, capture-safe

    int n_pix = in_sizes[0] / 3;                       // 524288
    prep_all<<<530, 256, 0, stream>>>(W1, W2, W3, emb, sidx, W0, b0, wp, c0);
    nilut_main<<<n_pix / 128, 512, 0, stream>>>(rgb, W0, b1, b2, b3, wp, c0, out, C);
}

// Round 7
// 276.243 us; speedup vs baseline: 1.2246x; 1.2246x over previous
//
#include <hip/hip_runtime.h>

#define HW  (512*512)

typedef _Float16 half8  __attribute__((__vector_size__(16)));
typedef float    floatx4 __attribute__((__vector_size__(16)));

__device__ __forceinline__ float gelu_f(float x){
    // gelu_tanh(x) = x * sigmoid(2c*(x + 0.044715 x^3)), c = sqrt(2/pi)
    float x2 = x * x;
    float q  = __builtin_fmaf(x2, -0.1029432f, -2.3022079f);
    float e  = __builtin_amdgcn_exp2f(x * q);
    return x * __builtin_amdgcn_rcpf(1.0f + e);
}

__device__ __forceinline__ float sigmoid_f(float x){
    float e = __builtin_amdgcn_exp2f(-1.44269504f * x);
    return __builtin_amdgcn_rcpf(1.0f + e);
}

// XOR swizzle: element (row, n) lives at f16 offset row*256 + (n ^ swz(row)).
// swz depends ONLY on row bits 2-3 (value bits 4-5), which (a) keeps A-frag
// b128 reads bank-balanced (8 lanes/16B-group, verified analytically),
// (b) keeps epilogue scalar writes 2-per-dword (free), and (c) makes the
// epilogue store address additive in m and r -> immediate-offset ds_write_b16.
__device__ __forceinline__ int swz(int row){
    return ((row >> 2) & 3) << 4;
}

// ---------------- prep: coalesced weight pack + per-batch c0 ----------
// blocks 0..63 : W1/W2 -> MFMA-B fragment order (f16), via LDS transpose.
//   dest element: blk512*512 + lane*8 + j  <->  W[k = ks*32+(lane>>4)*8+j][n = nt*16+(lane&15)]
// blocks 64..79: W3 padded [256][16] pack (tiny, scattered ok)
// blocks 80..81: c0[b][n] = emb[style_idx[b]] @ W0[3:67] + b0
__global__ void prep_all(const float* __restrict__ W1, const float* __restrict__ W2,
                         const float* __restrict__ W3, const float* __restrict__ emb,
                         const int* __restrict__ sidx, const float* __restrict__ W0,
                         const float* __restrict__ b0,
                         _Float16* __restrict__ wp, float* __restrict__ c0){
    __shared__ float ld[32][68];          // stride 68: 16B-aligned rows, bank-rotated
    int blk = blockIdx.x;
    int tid = threadIdx.x;
    if (blk < 64){
        int mat = blk >> 5;               // 0 = W1, 1 = W2
        int g   = blk & 31;
        int ks  = g >> 2;                 // 0..7
        int ntq = g & 3;                  // 0..3 (covers nt = ntq*4 .. ntq*4+3)
        const float* W = mat ? W2 : W1;
        int row = tid >> 3;               // 0..31 (k within ks block)
        int c8  = (tid & 7) * 8;          // 0..56 (n within 64-col stripe)
        const float* src = &W[(ks*32 + row)*256 + ntq*64 + c8];
        *(floatx4*)&ld[row][c8]     = *(const floatx4*)src;
        *(floatx4*)&ld[row][c8 + 4] = *(const floatx4*)(src + 4);
        __syncthreads();
        int lane = tid & 63;
        int nt_l = tid >> 6;              // 0..3
        half8 h;
        #pragma unroll
        for (int j = 0; j < 8; j++)
            h[j] = (_Float16)ld[(lane >> 4)*8 + j][nt_l*16 + (lane & 15)];
        _Float16* dst = wp + mat*65536 + (ks*16 + ntq*4 + nt_l)*512 + lane*8;
        *(half8*)dst = h;
    } else if (blk < 80){
        int i    = (blk - 64)*256 + tid;  // 0..4095, W3 padded [256][16]
        int j    = i & 7;
        int lane = (i >> 3) & 63;
        int ks   = i >> 9;                // 0..7
        int k = ks*32 + ((lane >> 4) << 3) + j;
        int n = lane & 15;
        wp[131072 + i] = (_Float16)((n < 3) ? W3[k*3 + n] : 0.0f);
    } else {
        int b = blk - 80;
        int s = sidx[b];
        float acc = b0[tid];
        #pragma unroll 8
        for (int d = 0; d < 64; d++)
            acc = fmaf(emb[s*64 + d], W0[(3 + d)*256 + tid], acc);
        c0[b*256 + tid] = acc;
    }
}

// ---------------- fused MLP ----------------
__global__ __launch_bounds__(512, 4)
void nilut_main(const float* __restrict__ rgb,
                const float* __restrict__ W0,
                const float* __restrict__ b1v,
                const float* __restrict__ b2v,
                const float* __restrict__ b3v,
                const _Float16* __restrict__ wp,
                const float* __restrict__ c0,
                float* __restrict__ out){
    __shared__ __align__(16) _Float16 act[128 * 256];   // 65536 B, XOR-swizzled
    __shared__ __align__(16) float    w0s[1024];        // W0 rows 0..2 | c0[b]; reused as out bounce
    __shared__ __align__(16) float    rgbs[384];        // staged rgb tile [3][128]

    const int tid = threadIdx.x;
    const int wg  = blockIdx.x;
    const int pixbase = wg * 128;
    const int b   = pixbase >> 18;        // HW = 2^18
    const int hw0 = pixbase & (HW - 1);

    // stage W0[0:3] + c0[b] into LDS
    #pragma unroll
    for (int r = 0; r < 2; r++){
        int q = r*512 + tid;
        w0s[q] = (q < 768) ? W0[q] : c0[b*256 + (q - 768)];
    }
    // stage rgb tile (coalesced: 3 runs of 128 contiguous floats)
    if (tid < 384){
        int c = tid >> 7, row = tid & 127;
        rgbs[tid] = rgb[b*3*HW + c*HW + hw0 + row];
    }
    __syncthreads();

    // ---- layer 0: coeffs in registers, 8 cols x 8 rows per thread ----
    {
        int ng = tid & 31;                // fixed col group: n = ng*8 .. ng*8+7
        int rg = tid >> 5;                // row group: rows rg*8 .. rg*8+7
        floatx4 cw[4][2];
        #pragma unroll
        for (int p = 0; p < 4; p++){
            cw[p][0] = *(const floatx4*)&w0s[p*256 + ng*8];
            cw[p][1] = *(const floatx4*)&w0s[p*256 + ng*8 + 4];
        }
        #pragma unroll
        for (int hf = 0; hf < 2; hf++){
            floatx4 rv[3];
            #pragma unroll
            for (int c = 0; c < 3; c++)
                rv[c] = *(const floatx4*)&rgbs[c*128 + rg*8 + hf*4];
            #pragma unroll
            for (int r4 = 0; r4 < 4; r4++){
                int row = rg*8 + hf*4 + r4;
                float rr = rv[0][r4], gg = rv[1][r4], bb = rv[2][r4];
                half8 v;
                #pragma unroll
                for (int j = 0; j < 8; j++){
                    int hi = j >> 2, lo = j & 3;
                    float z = fmaf(rr, cw[0][hi][lo],
                              fmaf(gg, cw[1][hi][lo],
                              fmaf(bb, cw[2][hi][lo], cw[3][hi][lo])));
                    v[j] = (_Float16)gelu_f(z);
                }
                *(half8*)&act[row*256 + ((ng*8) ^ swz(row))] = v;
            }
        }
    }
    __syncthreads();

    const int lane = tid & 63;
    const int wv   = tid >> 6;            // 0..7
    const int ln15 = lane & 15;
    const int quad = lane >> 4;
    const int q8   = quad * 8;
    const int qr   = quad * 4;
    const int sA   = swz(ln15);           // A-frag swizzle (row&15 == ln15), bits 4-5

    // ---- layers 1 and 2: 256x256 f16 MFMA, 2(row) x 4(col) wave split ----
    const _Float16* wl  = wp;             // Wp1
    const float* bias   = b1v;
    const int mh = wv >> 2, nh = wv & 3;
    const int rbase = mh * 64;
    const int cb16  = nh * 4;             // col base in 16-col units

    // epilogue store bases: addr = ebase[nt] + m*4096 + r*256 (f16 units),
    // all m/r offsets are compile-time immediates for ds_write_b16.
    int ebase[4];
    #pragma unroll
    for (int nt = 0; nt < 4; nt++)
        ebase[nt] = (rbase + qr)*256 + (((cb16 + nt)*16 + ln15) ^ (quad << 4));

    #pragma unroll 1
    for (int L = 0; L < 2; L++){
        floatx4 acc[4][4];
        #pragma unroll
        for (int nt = 0; nt < 4; nt++){
            float bv = bias[(cb16 + nt)*16 + ln15];
            #pragma unroll
            for (int m = 0; m < 4; m++)
                acc[m][nt] = (floatx4){bv, bv, bv, bv};
        }

        const half8* wp8 = (const half8*)wl;
        #pragma unroll 2
        for (int ks = 0; ks < 8; ks++){
            int k0 = (ks*32 + q8) ^ sA;
            half8 a[4];
            #pragma unroll
            for (int m = 0; m < 4; m++)
                a[m] = *(const half8*)&act[(rbase + m*16 + ln15)*256 + k0];
            #pragma unroll
            for (int nt = 0; nt < 4; nt++){
                half8 bf = wp8[(ks*16 + cb16 + nt)*64 + lane];
                #pragma unroll
                for (int m = 0; m < 4; m++)
                    acc[m][nt] = __builtin_amdgcn_mfma_f32_16x16x32_f16(a[m], bf, acc[m][nt], 0, 0, 0);
            }
        }
        __syncthreads();   // all reads of act done before overwrite
        #pragma unroll
        for (int nt = 0; nt < 4; nt++){
            #pragma unroll
            for (int m = 0; m < 4; m++){
                #pragma unroll
                for (int r = 0; r < 4; r++)
                    act[ebase[nt] + m*4096 + r*256] = (_Float16)gelu_f(acc[m][nt][r]);
            }
        }
        __syncthreads();
        wl = wp + 65536;   // Wp2
        bias = b2v;
    }

    // ---- final layer 256 -> 3 (padded to 16) + sigmoid ----
    {
        const half8* wp8 = (const half8*)(wp + 131072);
        int rbf = wv * 16;                 // 8 waves x 16 rows = 128
        floatx4 ac = (floatx4){0.f,0.f,0.f,0.f};
        #pragma unroll
        for (int ks = 0; ks < 8; ks++){
            int k0 = (ks*32 + q8) ^ sA;
            half8 a  = *(const half8*)&act[(rbf + ln15)*256 + k0];
            half8 bf = wp8[ks*64 + lane];
            ac = __builtin_amdgcn_mfma_f32_16x16x32_f16(a, bf, ac, 0, 0, 0);
        }
        // w0s dead since layer 0 -> reuse as out bounce [3][128]
        if (ln15 < 3){
            float bv = b3v[ln15];
            #pragma unroll
            for (int r = 0; r < 4; r++){
                int row0 = rbf + qr + r;
                w0s[ln15*128 + row0] = sigmoid_f(ac[r] + bv);
            }
        }
        __syncthreads();
        if (tid < 96){
            int c  = tid >> 5;
            int i2 = tid & 31;
            float4* dst = (float4*)(out + (b*3 + c)*HW + hw0);
            dst[i2] = ((float4*)(w0s + c*128))[i2];
        }
    }
}

extern "C" void kernel_launch(void* const* d_in, const int* in_sizes, int n_in,
                              void* d_out, int out_size, void* d_ws, size_t ws_size,
                              hipStream_t stream){
    const float* rgb = (const float*)d_in[0];
    const int*  sidx = (const int*) d_in[1];
    const float* emb = (const float*)d_in[2];
    const float* W0  = (const float*)d_in[3];
    const float* b0  = (const float*)d_in[4];
    const float* W1  = (const float*)d_in[5];
    const float* b1  = (const float*)d_in[6];
    const float* W2  = (const float*)d_in[7];
    const float* b2  = (const float*)d_in[8];
    const float* W3  = (const float*)d_in[9];
    const float* b3  = (const float*)d_in[10];
    float* out = (float*)d_out;

    _Float16* wp = (_Float16*)d_ws;                    // 135168 f16 = 270336 B
    float*    c0 = (float*)((char*)d_ws + 270336);     // 512 f32

    int n_pix = in_sizes[0] / 3;                       // 524288
    prep_all<<<82, 256, 0, stream>>>(W1, W2, W3, emb, sidx, W0, b0, wp, c0);
    nilut_main<<<n_pix / 128, 512, 0, stream>>>(rgb, W0, b1, b2, b3, wp, c0, out);
}

// Round 8
// 272.729 us; speedup vs baseline: 1.2404x; 1.0129x over previous
//
#include <hip/hip_runtime.h>

#define HW  (512*512)

typedef _Float16 half8  __attribute__((__vector_size__(16)));
typedef float    floatx4 __attribute__((__vector_size__(16)));

__device__ __forceinline__ float gelu_f(float x){
    // gelu_tanh(x) = x * sigmoid(2c*(x + 0.044715 x^3)), c = sqrt(2/pi)
    float x2 = x * x;
    float q  = __builtin_fmaf(x2, -0.1029432f, -2.3022079f);
    float e  = __builtin_amdgcn_exp2f(x * q);
    return x * __builtin_amdgcn_rcpf(1.0f + e);
}

__device__ __forceinline__ float sigmoid_f(float x){
    float e = __builtin_amdgcn_exp2f(-1.44269504f * x);
    return __builtin_amdgcn_rcpf(1.0f + e);
}

// XOR swizzle: element (row, n) lives at f16 offset row*256 + (n ^ swz(row)).
// Depends only on row bits 2-3 -> epilogue stores are immediate-offset in m,r.
__device__ __forceinline__ int swz(int row){
    return ((row >> 2) & 3) << 4;
}

// ---------------- prep: coalesced weight pack + per-batch c0 ----------
__global__ void prep_all(const float* __restrict__ W1, const float* __restrict__ W2,
                         const float* __restrict__ W3, const float* __restrict__ emb,
                         const int* __restrict__ sidx, const float* __restrict__ W0,
                         const float* __restrict__ b0,
                         _Float16* __restrict__ wp, float* __restrict__ c0){
    __shared__ float ld[32][68];          // stride 68: 16B-aligned rows, bank-rotated
    int blk = blockIdx.x;
    int tid = threadIdx.x;
    if (blk < 64){
        int mat = blk >> 5;               // 0 = W1, 1 = W2
        int g   = blk & 31;
        int ks  = g >> 2;                 // 0..7
        int ntq = g & 3;                  // 0..3
        const float* W = mat ? W2 : W1;
        int row = tid >> 3;               // 0..31
        int c8  = (tid & 7) * 8;          // 0..56
        const float* src = &W[(ks*32 + row)*256 + ntq*64 + c8];
        *(floatx4*)&ld[row][c8]     = *(const floatx4*)src;
        *(floatx4*)&ld[row][c8 + 4] = *(const floatx4*)(src + 4);
        __syncthreads();
        int lane = tid & 63;
        int nt_l = tid >> 6;              // 0..3
        half8 h;
        #pragma unroll
        for (int j = 0; j < 8; j++)
            h[j] = (_Float16)ld[(lane >> 4)*8 + j][nt_l*16 + (lane & 15)];
        _Float16* dst = wp + mat*65536 + (ks*16 + ntq*4 + nt_l)*512 + lane*8;
        *(half8*)dst = h;
    } else if (blk < 80){
        int i    = (blk - 64)*256 + tid;  // W3 padded [256][16]
        int j    = i & 7;
        int lane = (i >> 3) & 63;
        int ks   = i >> 9;
        int k = ks*32 + ((lane >> 4) << 3) + j;
        int n = lane & 15;
        wp[131072 + i] = (_Float16)((n < 3) ? W3[k*3 + n] : 0.0f);
    } else {
        int b = blk - 80;
        int s = sidx[b];
        float acc = b0[tid];
        #pragma unroll 8
        for (int d = 0; d < 64; d++)
            acc = fmaf(emb[s*64 + d], W0[(3 + d)*256 + tid], acc);
        c0[b*256 + tid] = acc;
    }
}

// ---------------- fused MLP: 64-pixel tile, 256 threads (4 waves) ----------
// 4 blocks/CU (LDS ~38 KB) -> 4 independent barrier domains per CU for
// cross-block phase overlap; per-thread work identical to the 128-tile version.
__global__ __launch_bounds__(256, 4)
void nilut_main(const float* __restrict__ rgb,
                const float* __restrict__ W0,
                const float* __restrict__ b1v,
                const float* __restrict__ b2v,
                const float* __restrict__ b3v,
                const _Float16* __restrict__ wp,
                const float* __restrict__ c0,
                float* __restrict__ out){
    __shared__ __align__(16) _Float16 act[64 * 256];    // 32768 B, XOR-swizzled
    __shared__ __align__(16) float    w0s[1024];        // W0 rows 0..2 | c0[b]; reused as out bounce
    __shared__ __align__(16) float    rgbs[192];        // staged rgb tile [3][64]

    const int tid = threadIdx.x;
    const int wg  = blockIdx.x;
    const int pixbase = wg * 64;
    const int b   = pixbase >> 18;        // HW = 2^18
    const int hw0 = pixbase & (HW - 1);

    // stage W0[0:3] + c0[b] into LDS
    #pragma unroll
    for (int r = 0; r < 4; r++){
        int q = r*256 + tid;
        w0s[q] = (q < 768) ? W0[q] : c0[b*256 + (q - 768)];
    }
    // stage rgb tile (3 runs of 64 contiguous floats)
    if (tid < 192){
        int c = tid >> 6, row = tid & 63;
        rgbs[tid] = rgb[b*3*HW + c*HW + hw0 + row];
    }
    __syncthreads();

    // ---- layer 0: coeffs in registers, 8 cols x 8 rows per thread ----
    {
        int ng = tid & 31;                // col group: n = ng*8 .. ng*8+7
        int rg = tid >> 5;                // row group 0..7: rows rg*8 .. rg*8+7
        floatx4 cw[4][2];
        #pragma unroll
        for (int p = 0; p < 4; p++){
            cw[p][0] = *(const floatx4*)&w0s[p*256 + ng*8];
            cw[p][1] = *(const floatx4*)&w0s[p*256 + ng*8 + 4];
        }
        #pragma unroll
        for (int hf = 0; hf < 2; hf++){
            floatx4 rv[3];
            #pragma unroll
            for (int c = 0; c < 3; c++)
                rv[c] = *(const floatx4*)&rgbs[c*64 + rg*8 + hf*4];
            #pragma unroll
            for (int r4 = 0; r4 < 4; r4++){
                int row = rg*8 + hf*4 + r4;
                float rr = rv[0][r4], gg = rv[1][r4], bb = rv[2][r4];
                half8 v;
                #pragma unroll
                for (int j = 0; j < 8; j++){
                    int hi = j >> 2, lo = j & 3;
                    float z = fmaf(rr, cw[0][hi][lo],
                              fmaf(gg, cw[1][hi][lo],
                              fmaf(bb, cw[2][hi][lo], cw[3][hi][lo])));
                    v[j] = (_Float16)gelu_f(z);
                }
                *(half8*)&act[row*256 + ((ng*8) ^ swz(row))] = v;
            }
        }
    }
    __syncthreads();

    const int lane = tid & 63;
    const int wv   = tid >> 6;            // 0..3
    const int ln15 = lane & 15;
    const int quad = lane >> 4;
    const int q8   = quad * 8;
    const int qr   = quad * 4;
    const int sA   = swz(ln15);           // A-frag swizzle

    // ---- layers 1 and 2: 64x256x256 f16 MFMA, 1(row) x 4(col) wave split ----
    const _Float16* wl  = wp;             // Wp1
    const float* bias   = b1v;
    const int cb16  = wv * 4;             // col base in 16-col units

    // epilogue store: addr = ebase[nt] + m*4096 + r*256 (f16), immediates in m,r
    int ebase[4];
    #pragma unroll
    for (int nt = 0; nt < 4; nt++)
        ebase[nt] = qr*256 + (((cb16 + nt)*16 + ln15) ^ (quad << 4));

    #pragma unroll 1
    for (int L = 0; L < 2; L++){
        floatx4 acc[4][4];
        #pragma unroll
        for (int nt = 0; nt < 4; nt++){
            float bv = bias[(cb16 + nt)*16 + ln15];
            #pragma unroll
            for (int m = 0; m < 4; m++)
                acc[m][nt] = (floatx4){bv, bv, bv, bv};
        }

        const half8* wp8 = (const half8*)wl;
        #pragma unroll 2
        for (int ks = 0; ks < 8; ks++){
            int k0 = (ks*32 + q8) ^ sA;
            half8 a[4];
            #pragma unroll
            for (int m = 0; m < 4; m++)
                a[m] = *(const half8*)&act[(m*16 + ln15)*256 + k0];
            #pragma unroll
            for (int nt = 0; nt < 4; nt++){
                half8 bf = wp8[(ks*16 + cb16 + nt)*64 + lane];
                #pragma unroll
                for (int m = 0; m < 4; m++)
                    acc[m][nt] = __builtin_amdgcn_mfma_f32_16x16x32_f16(a[m], bf, acc[m][nt], 0, 0, 0);
            }
        }
        __syncthreads();   // all reads of act done before overwrite
        #pragma unroll
        for (int nt = 0; nt < 4; nt++){
            #pragma unroll
            for (int m = 0; m < 4; m++){
                #pragma unroll
                for (int r = 0; r < 4; r++)
                    act[ebase[nt] + m*4096 + r*256] = (_Float16)gelu_f(acc[m][nt][r]);
            }
        }
        __syncthreads();
        wl = wp + 65536;   // Wp2
        bias = b2v;
    }

    // ---- final layer 256 -> 3 (padded to 16) + sigmoid ----
    {
        const half8* wp8 = (const half8*)(wp + 131072);
        int rbf = wv * 16;                 // 4 waves x 16 rows = 64
        floatx4 ac = (floatx4){0.f,0.f,0.f,0.f};
        #pragma unroll
        for (int ks = 0; ks < 8; ks++){
            int k0 = (ks*32 + q8) ^ sA;
            half8 a  = *(const half8*)&act[(rbf + ln15)*256 + k0];
            half8 bf = wp8[ks*64 + lane];
            ac = __builtin_amdgcn_mfma_f32_16x16x32_f16(a, bf, ac, 0, 0, 0);
        }
        // w0s dead since layer 0 -> reuse as out bounce [3][64]
        if (ln15 < 3){
            float bv = b3v[ln15];
            #pragma unroll
            for (int r = 0; r < 4; r++){
                int row0 = rbf + qr + r;
                w0s[ln15*64 + row0] = sigmoid_f(ac[r] + bv);
            }
        }
        __syncthreads();
        if (tid < 48){
            int c  = tid >> 4;
            int i2 = tid & 15;
            float4* dst = (float4*)(out + (b*3 + c)*HW + hw0);
            dst[i2] = ((float4*)(w0s + c*64))[i2];
        }
    }
}

extern "C" void kernel_launch(void* const* d_in, const int* in_sizes, int n_in,
                              void* d_out, int out_size, void* d_ws, size_t ws_size,
                              hipStream_t stream){
    const float* rgb = (const float*)d_in[0];
    const int*  sidx = (const int*) d_in[1];
    const float* emb = (const float*)d_in[2];
    const float* W0  = (const float*)d_in[3];
    const float* b0  = (const float*)d_in[4];
    const float* W1  = (const float*)d_in[5];
    const float* b1  = (const float*)d_in[6];
    const float* W2  = (const float*)d_in[7];
    const float* b2  = (const float*)d_in[8];
    const float* W3  = (const float*)d_in[9];
    const float* b3  = (const float*)d_in[10];
    float* out = (float*)d_out;

    _Float16* wp = (_Float16*)d_ws;                    // 135168 f16 = 270336 B
    float*    c0 = (float*)((char*)d_ws + 270336);     // 512 f32

    int n_pix = in_sizes[0] / 3;                       // 524288
    prep_all<<<82, 256, 0, stream>>>(W1, W2, W3, emb, sidx, W0, b0, wp, c0);
    nilut_main<<<n_pix / 64, 256, 0, stream>>>(rgb, W0, b1, b2, b3, wp, c0, out);
}

// Round 9
// 266.241 us; speedup vs baseline: 1.2706x; 1.0244x over previous
//
#include <hip/hip_runtime.h>

#define HW  (512*512)

typedef _Float16 half8  __attribute__((__vector_size__(16)));
typedef _Float16 half4  __attribute__((__vector_size__(8)));
typedef _Float16 half2_t __attribute__((__vector_size__(4)));
typedef float    floatx4 __attribute__((__vector_size__(16)));

__device__ __forceinline__ float gelu_f(float x){
    // gelu_tanh(x) = x * sigmoid(2c*(x + 0.044715 x^3)), c = sqrt(2/pi)
    float x2 = x * x;
    float q  = __builtin_fmaf(x2, -0.1029432f, -2.3022079f);
    float e  = __builtin_amdgcn_exp2f(x * q);
    return x * __builtin_amdgcn_rcpf(1.0f + e);
}

__device__ __forceinline__ float sigmoid_f(float x){
    float e = __builtin_amdgcn_exp2f(-1.44269504f * x);
    return __builtin_amdgcn_rcpf(1.0f + e);
}

// act layout: element (px, n) lives at f16 offset px*256 + ((n>>3) ^ (px&7))*8 + (n&7).
// 3-bit chunk XOR keeps b128 B-frag reads 8-lane/4-bank balanced and b64
// epilogue writes at optimal 4 accesses/bank (verified analytically).

// ---------------- prep: coalesced weight pack + per-batch c0 ----------
// Packed block (ks, mt) element at lane*8+j  <->  W[k=ks*32+(lane>>4)*8+j][n_out=mt*16+(lane&15)]
// Serves as the MFMA *A* operand now (A[m=n_out=ln15][k=quad*8+j]) — same bytes as before.
__global__ void prep_all(const float* __restrict__ W1, const float* __restrict__ W2,
                         const float* __restrict__ W3, const float* __restrict__ emb,
                         const int* __restrict__ sidx, const float* __restrict__ W0,
                         const float* __restrict__ b0,
                         _Float16* __restrict__ wp, float* __restrict__ c0){
    __shared__ float ld[32][68];          // stride 68: 16B-aligned rows, bank-rotated
    int blk = blockIdx.x;
    int tid = threadIdx.x;
    if (blk < 64){
        int mat = blk >> 5;               // 0 = W1, 1 = W2
        int g   = blk & 31;
        int ks  = g >> 2;                 // 0..7
        int ntq = g & 3;                  // 0..3
        const float* W = mat ? W2 : W1;
        int row = tid >> 3;               // 0..31
        int c8  = (tid & 7) * 8;          // 0..56
        const float* src = &W[(ks*32 + row)*256 + ntq*64 + c8];
        *(floatx4*)&ld[row][c8]     = *(const floatx4*)src;
        *(floatx4*)&ld[row][c8 + 4] = *(const floatx4*)(src + 4);
        __syncthreads();
        int lane = tid & 63;
        int nt_l = tid >> 6;              // 0..3
        half8 h;
        #pragma unroll
        for (int j = 0; j < 8; j++)
            h[j] = (_Float16)ld[(lane >> 4)*8 + j][nt_l*16 + (lane & 15)];
        _Float16* dst = wp + mat*65536 + (ks*16 + ntq*4 + nt_l)*512 + lane*8;
        *(half8*)dst = h;
    } else if (blk < 80){
        int i    = (blk - 64)*256 + tid;  // W3 padded [256][16]
        int j    = i & 7;
        int lane = (i >> 3) & 63;
        int ks   = i >> 9;
        int k = ks*32 + ((lane >> 4) << 3) + j;
        int n = lane & 15;
        wp[131072 + i] = (_Float16)((n < 3) ? W3[k*3 + n] : 0.0f);
    } else {
        int b = blk - 80;
        int s = sidx[b];
        float acc = b0[tid];
        #pragma unroll 8
        for (int d = 0; d < 64; d++)
            acc = fmaf(emb[s*64 + d], W0[(3 + d)*256 + tid], acc);
        c0[b*256 + tid] = acc;
    }
}

// ---------------- fused MLP: 64-pixel tile, 256 threads (4 waves) ----------
// Hidden layers compute D = Wpacked(A) * act(B): D rows = output neurons,
// D cols = pixels -> each lane holds 4 consecutive neurons of one pixel ->
// epilogue is ds_write_b64 instead of 4x ds_write_b16.
__global__ __launch_bounds__(256, 4)
void nilut_main(const float* __restrict__ rgb,
                const float* __restrict__ W0,
                const float* __restrict__ b1v,
                const float* __restrict__ b2v,
                const float* __restrict__ b3v,
                const _Float16* __restrict__ wp,
                const float* __restrict__ c0,
                float* __restrict__ out){
    __shared__ __align__(16) _Float16 act[64 * 256];    // 32768 B, chunk-XOR swizzled
    __shared__ __align__(16) float    w0s[1024];        // W0 rows 0..2 | c0[b]; reused as out bounce
    __shared__ __align__(16) float    rgbs[192];        // staged rgb tile [3][64]

    const int tid = threadIdx.x;
    const int wg  = blockIdx.x;
    const int pixbase = wg * 64;
    const int b   = pixbase >> 18;        // HW = 2^18
    const int hw0 = pixbase & (HW - 1);

    // stage W0[0:3] + c0[b] into LDS
    #pragma unroll
    for (int r = 0; r < 4; r++){
        int q = r*256 + tid;
        w0s[q] = (q < 768) ? W0[q] : c0[b*256 + (q - 768)];
    }
    // stage rgb tile (3 runs of 64 contiguous floats)
    if (tid < 192){
        int c = tid >> 6, row = tid & 63;
        rgbs[tid] = rgb[b*3*HW + c*HW + hw0 + row];
    }
    __syncthreads();

    // ---- layer 0: coeffs in registers, 8 cols x 8 rows per thread ----
    {
        int ng = tid & 31;                // chunk index: cols ng*8 .. ng*8+7
        int rg = tid >> 5;                // row group 0..7
        floatx4 cw[4][2];
        #pragma unroll
        for (int p = 0; p < 4; p++){
            cw[p][0] = *(const floatx4*)&w0s[p*256 + ng*8];
            cw[p][1] = *(const floatx4*)&w0s[p*256 + ng*8 + 4];
        }
        #pragma unroll
        for (int hf = 0; hf < 2; hf++){
            floatx4 rv[3];
            #pragma unroll
            for (int c = 0; c < 3; c++)
                rv[c] = *(const floatx4*)&rgbs[c*64 + rg*8 + hf*4];
            #pragma unroll
            for (int r4 = 0; r4 < 4; r4++){
                int row = rg*8 + hf*4 + r4;
                float rr = rv[0][r4], gg = rv[1][r4], bb = rv[2][r4];
                half8 v;
                #pragma unroll
                for (int j = 0; j < 8; j++){
                    int hi = j >> 2, lo = j & 3;
                    float z = fmaf(rr, cw[0][hi][lo],
                              fmaf(gg, cw[1][hi][lo],
                              fmaf(bb, cw[2][hi][lo], cw[3][hi][lo])));
                    v[j] = (_Float16)gelu_f(z);
                }
                *(half8*)&act[row*256 + ((ng ^ (row & 7)) << 3)] = v;
            }
        }
    }
    __syncthreads();

    const int lane = tid & 63;
    const int wv   = tid >> 6;            // 0..3
    const int ln15 = lane & 15;
    const int quad = lane >> 4;
    const int qr   = quad * 4;
    const int sx   = ln15 & 7;            // swizzle key (px & 7)
    const int qx8  = (quad ^ (sx & 3)) * 8;
    const int kb32 = ((sx >> 2) & 1) << 5;   // k-chunk XOR bit, f16 units

    // B-frag (act) read base per pixel tile: addr = pbq[pt] + ((ks<<5) ^ kb32)
    int pbq[4];
    #pragma unroll
    for (int pt = 0; pt < 4; pt++)
        pbq[pt] = (pt*16 + ln15)*256 + qx8;

    // epilogue write: addr = eb[pt] + cx[mtl] (b64, 4 consecutive neurons)
    const int qh = quad >> 1, qs = (quad & 1) * 4;
    int eb[4];
    #pragma unroll
    for (int pt = 0; pt < 4; pt++)
        eb[pt] = (pt*16 + ln15)*256 + qs;

    // ---- layers 1 and 2: D = W(A) x act(B), wave wv owns n_out tiles wv*4..+3 ----
    const _Float16* wl  = wp;             // Wp1
    const float* bias   = b1v;
    #pragma unroll 1
    for (int L = 0; L < 2; L++){
        floatx4 acc[4][4];                // [pt][mtl]
        #pragma unroll
        for (int mtl = 0; mtl < 4; mtl++){
            floatx4 bv = *(const floatx4*)&bias[(wv*4 + mtl)*16 + qr];
            #pragma unroll
            for (int pt = 0; pt < 4; pt++)
                acc[pt][mtl] = bv;
        }

        const half8* wp8 = (const half8*)wl;
        #pragma unroll 2
        for (int ks = 0; ks < 8; ks++){
            int t = (ks << 5) ^ kb32;
            half8 bfr[4];
            #pragma unroll
            for (int pt = 0; pt < 4; pt++)
                bfr[pt] = *(const half8*)&act[pbq[pt] + t];
            #pragma unroll
            for (int mtl = 0; mtl < 4; mtl++){
                half8 af = wp8[(ks*16 + wv*4 + mtl)*64 + lane];
                #pragma unroll
                for (int pt = 0; pt < 4; pt++)
                    acc[pt][mtl] = __builtin_amdgcn_mfma_f32_16x16x32_f16(af, bfr[pt], acc[pt][mtl], 0, 0, 0);
            }
        }
        __syncthreads();   // all reads of act done before overwrite
        #pragma unroll
        for (int mtl = 0; mtl < 4; mtl++){
            int cx = (((wv*4 + mtl)*2 + qh) ^ sx) << 3;
            #pragma unroll
            for (int pt = 0; pt < 4; pt++){
                floatx4 v = acc[pt][mtl];
                half2_t g01 = __builtin_amdgcn_cvt_pkrtz(gelu_f(v[0]), gelu_f(v[1]));
                half2_t g23 = __builtin_amdgcn_cvt_pkrtz(gelu_f(v[2]), gelu_f(v[3]));
                half4 h;
                h[0] = g01[0]; h[1] = g01[1]; h[2] = g23[0]; h[3] = g23[1];
                *(half4*)&act[eb[pt] + cx] = h;
            }
        }
        __syncthreads();
        wl = wp + 65536;   // Wp2
        bias = b2v;
    }

    // ---- final layer 256 -> 3 (padded to 16) + sigmoid ----
    {
        const half8* wp8 = (const half8*)(wp + 131072);
        floatx4 ac = (floatx4){0.f,0.f,0.f,0.f};
        int pb = (wv*16 + ln15)*256 + qx8;   // this wave's pixel tile
        #pragma unroll
        for (int ks = 0; ks < 8; ks++){
            half8 bfr = *(const half8*)&act[pb + ((ks << 5) ^ kb32)];
            half8 af  = wp8[ks*64 + lane];
            ac = __builtin_amdgcn_mfma_f32_16x16x32_f16(af, bfr, ac, 0, 0, 0);
        }
        // D rows = channel (qr+r), col = pixel ln15; only quad 0 rows 0..2 valid.
        // w0s dead since layer 0 -> reuse as out bounce [3][64]
        if (quad == 0){
            #pragma unroll
            for (int r = 0; r < 3; r++)
                w0s[r*64 + wv*16 + ln15] = sigmoid_f(ac[r] + b3v[r]);
        }
        __syncthreads();
        if (tid < 48){
            int c  = tid >> 4;
            int i2 = tid & 15;
            float4* dst = (float4*)(out + (b*3 + c)*HW + hw0);
            dst[i2] = ((float4*)(w0s + c*64))[i2];
        }
    }
}

extern "C" void kernel_launch(void* const* d_in, const int* in_sizes, int n_in,
                              void* d_out, int out_size, void* d_ws, size_t ws_size,
                              hipStream_t stream){
    const float* rgb = (const float*)d_in[0];
    const int*  sidx = (const int*) d_in[1];
    const float* emb = (const float*)d_in[2];
    const float* W0  = (const float*)d_in[3];
    const float* b0  = (const float*)d_in[4];
    const float* W1  = (const float*)d_in[5];
    const float* b1  = (const float*)d_in[6];
    const float* W2  = (const float*)d_in[7];
    const float* b2  = (const float*)d_in[8];
    const float* W3  = (const float*)d_in[9];
    const float* b3  = (const float*)d_in[10];
    float* out = (float*)d_out;

    _Float16* wp = (_Float16*)d_ws;                    // 135168 f16 = 270336 B
    float*    c0 = (float*)((char*)d_ws + 270336);     // 512 f32

    int n_pix = in_sizes[0] / 3;                       // 524288
    prep_all<<<82, 256, 0, stream>>>(W1, W2, W3, emb, sidx, W0, b0, wp, c0);
    nilut_main<<<n_pix / 64, 256, 0, stream>>>(rgb, W0, b1, b2, b3, wp, c0, out);
}